// Round 1
// 365.063 us; speedup vs baseline: 1.0255x; 1.0255x over previous
//
#include <hip/hip_runtime.h>

// Problem constants
#define BB 4
#define SS 2048
#define DD 1024   // DIM_IN = DIM_Q = DIM_V = 1024

typedef __attribute__((ext_vector_type(8))) short short8;
typedef __attribute__((ext_vector_type(4))) float f32x4;

__device__ __forceinline__ unsigned short f2b(float f) {
  unsigned u = __builtin_bit_cast(unsigned, f);
  u += 0x7fffu + ((u >> 16) & 1u);   // RNE
  return (unsigned short)(u >> 16);
}
__device__ __forceinline__ float b2f(unsigned short us) {
  unsigned u = (unsigned)us << 16;
  return __builtin_bit_cast(float, u);
}

__device__ __forceinline__ void gl2lds16(const void* g, void* l) {
  __builtin_amdgcn_global_load_lds(
      (__attribute__((address_space(1))) unsigned int*)(void*)(size_t)(uintptr_t)g,
      (__attribute__((address_space(3))) unsigned int*)l, 16, 0, 0);
}

// -------- fp32 -> bf16 convert for 3 inputs (x<4096) and 3 weights (x>=4096)
__global__ __launch_bounds__(256) void cvt_all(
    const float* __restrict__ q, const float* __restrict__ k, const float* __restrict__ v,
    const float* __restrict__ wq, const float* __restrict__ wk, const float* __restrict__ wv,
    unsigned short* __restrict__ qo, unsigned short* __restrict__ ko, unsigned short* __restrict__ vo,
    unsigned short* __restrict__ wqo, unsigned short* __restrict__ wko, unsigned short* __restrict__ wvo) {
  const int z = blockIdx.z;
  const float* s;
  unsigned short* d;
  size_t i;
  if (blockIdx.x < 4096) {
    s = z == 0 ? q : (z == 1 ? k : v);
    d = z == 0 ? qo : (z == 1 ? ko : vo);
    i = (size_t)blockIdx.x * 2048 + threadIdx.x * 8;
  } else {
    s = z == 0 ? wq : (z == 1 ? wk : wv);
    d = z == 0 ? wqo : (z == 1 ? wko : wvo);
    i = (size_t)(blockIdx.x - 4096) * 2048 + threadIdx.x * 8;
  }
  float4 a = *(const float4*)(s + i);
  float4 b = *(const float4*)(s + i + 4);
  union { unsigned short us[8]; uint4 v4; } o;
  o.us[0] = f2b(a.x); o.us[1] = f2b(a.y); o.us[2] = f2b(a.z); o.us[3] = f2b(a.w);
  o.us[4] = f2b(b.x); o.us[5] = f2b(b.y); o.us[6] = f2b(b.z); o.us[7] = f2b(b.w);
  *(uint4*)(d + i) = o.v4;
}

// ================= 256x256 8-phase BT-layout bf16 GEMM =====================
// C[m][n] = sum_k A[m][k]*B[n][k].  BM=BN=256, BK=64, 512 threads (8 waves,
// 2x4), per-wave output 128x64 (rows wr*64 + mh*128 quadrant scheme).
// LDS 128 KiB: buf{0,1} x {A0,A1,B0,B1} 16KB regions (each 128 rows x 64 k),
// stored as 16x32-bf16 subtiles (1024B) with st_16x32 XOR swizzle
// (byte ^= ((byte>>9)&1)<<5), applied as inverse-swizzled GLOBAL source +
// swizzled ds_read address (LDS dest of global_load_lds stays linear).
//
// Stage/liveness ledger (iter i computes tile t0=2i from buf0 in p1-4,
// t1=2i+1 from buf1 in p5-8; quadrant order p1..p4 = (mh,nh)=(0,0),(0,1),
// (1,0),(1,1); A-half mh dead after its nh=1 phase, B-half nh dead after its
// mh=1 phase):
//   p1: stage buf1.A1<-t1   (buf1.A1 dead after prev p8)
//   p2: stage buf1.B1<-t1   (dead after prev p8)
//   p3: stage buf0.A0<-t0+2 (dead after p2)
//   p4: stage buf0.B0<-t0+2 (dead after p3); vmcnt(4) -> all 4 t1 halves
//       landed (issued prev-p7,prev-p8,p1,p2; only p3,p4 remain in flight)
//   p5: stage buf0.A1<-t0+2   p6: stage buf0.B1<-t0+2
//   p7: stage buf1.A0<-t1+2   p8: stage buf1.B0<-t1+2; vmcnt(4) -> all of
//       t0+2 landed before next-iter p1.
// Each barrier pair per phase: [reads issued, stage issued] BAR [MFMA] BAR —
// the post-MFMA barrier guarantees every wave's ds_reads of a region
// completed (lgkm drained before its MFMA) before any wave stages over it.
enum { EPI_BIAS_COL = 0, EPI_BIAS_ROW = 1, EPI_SCORE = 2, EPI_OUT = 3 };

#define BAR() asm volatile("s_barrier" ::: "memory")
#define VMW4() asm volatile("s_waitcnt vmcnt(4)" ::: "memory")
#define VMW0() asm volatile("s_waitcnt vmcnt(0)" ::: "memory")

#define MMA_QUAD(MH, NH)                                                       \
  do {                                                                         \
    __builtin_amdgcn_s_setprio(1);                                             \
    _Pragma("unroll") for (int mt = 0; mt < 4; ++mt)                           \
        _Pragma("unroll") for (int nt = 0; nt < 2; ++nt)                       \
            _Pragma("unroll") for (int ks = 0; ks < 2; ++ks)                   \
                acc[MH][NH][mt][nt] = __builtin_amdgcn_mfma_f32_16x16x32_bf16( \
                    afr[mt][ks], bfr[nt][ks], acc[MH][NH][mt][nt], 0, 0, 0);   \
    __builtin_amdgcn_s_setprio(0);                                             \
  } while (0)

template <int EPI>
__global__ __launch_bounds__(512, 2) void gemm256(
    const unsigned short* __restrict__ A, int lda, long long aBatch,
    const unsigned short* __restrict__ Bm, int ldb, long long bBatch,
    void* __restrict__ Cv, int ldc, long long cBatch, int K,
    const float* __restrict__ bias,   // z==0 bias (or the only one)
    const float* __restrict__ bias2,  // z==1 bias for batched q/k dispatch
    float scale) {
  __shared__ __attribute__((aligned(128))) char lds[131072];
  const int tid = threadIdx.x;
  const int wave = tid >> 6, lane = tid & 63;
  const int l15 = lane & 15, quad = lane >> 4;
  const int wr = wave >> 2, wc = wave & 3;   // 2x4 wave grid
  const int bm = blockIdx.x * 256, bn = blockIdx.y * 256, z = blockIdx.z;
  A += (long long)z * aBatch;
  Bm += (long long)z * bBatch;

  // ds_read byte offset within a 16x32 subtile for fragment (row=l15, k=quad*8):
  // (l15&15)*64 + quad*16, bit9 = l15&8 -> XOR byte bit5.
  const int laneterm = l15 * 64 + ((quad * 16) ^ ((l15 & 8) << 2));

  // Staging: dest slot s = tid + i*512 (16B units, linear). Source element =
  // linear element at slot s ^ (((s>>5)&1)<<1)  (byte bit9->slot bit5,
  // byte bit5->slot bit1; involution).  slot -> (row,k): subtile st=s>>6
  // (8 subtile-rows x 2 subtile-cols), row=(st>>1)*16 + ((s>>2)&15),
  // k=(st&1)*32 + (s&3)*8.
  size_t aoff0, aoff1, boff0, boff1;
  int dst0, dst1;
  {
    int s = tid, s2 = s ^ (((s >> 5) & 1) << 1);
    int row = (s2 >> 7) * 16 + ((s2 >> 2) & 15);
    int col = ((s2 >> 6) & 1) * 32 + (s2 & 3) * 8;
    aoff0 = (size_t)(bm + row) * lda + col;
    boff0 = (size_t)(bn + row) * ldb + col;
    dst0 = (tid & ~63) * 16;            // wave-uniform; HW adds lane*16B
    s = tid + 512; s2 = s ^ (((s >> 5) & 1) << 1);
    row = (s2 >> 7) * 16 + ((s2 >> 2) & 15);
    col = ((s2 >> 6) & 1) * 32 + (s2 & 3) * 8;
    aoff1 = (size_t)(bm + row) * lda + col;
    boff1 = (size_t)(bn + row) * ldb + col;
    dst1 = (tid & ~63) * 16 + 8192;
  }

  auto stageA = [&](int buf, int half, int t) {
    const unsigned short* s0 = A + aoff0 + (size_t)(half * 128) * lda + t * 64;
    const unsigned short* s1 = A + aoff1 + (size_t)(half * 128) * lda + t * 64;
    char* d = lds + buf * 65536 + half * 16384;
    gl2lds16(s0, d + dst0);
    gl2lds16(s1, d + dst1);
  };
  auto stageB = [&](int buf, int half, int t) {
    const unsigned short* s0 = Bm + boff0 + (size_t)(half * 128) * ldb + t * 64;
    const unsigned short* s1 = Bm + boff1 + (size_t)(half * 128) * ldb + t * 64;
    char* d = lds + 32768 + buf * 65536 + half * 16384;
    gl2lds16(s0, d + dst0);
    gl2lds16(s1, d + dst1);
  };

  f32x4 acc[2][2][4][2] = {};   // [mh][nh][mt][nt]
  short8 afr[4][2], bfr[2][2];  // [mt][ks], [nt][ks]

  auto loadA = [&](int buf, int mh) {
    const char* rg = lds + buf * 65536 + mh * 16384;
#pragma unroll
    for (int mt = 0; mt < 4; ++mt)
#pragma unroll
      for (int ks = 0; ks < 2; ++ks)
        afr[mt][ks] = *(const short8*)(rg + ((wr * 4 + mt) * 2 + ks) * 1024 + laneterm);
  };
  auto loadB = [&](int buf, int nh) {
    const char* rg = lds + 32768 + buf * 65536 + nh * 16384;
#pragma unroll
    for (int nt = 0; nt < 2; ++nt)
#pragma unroll
      for (int ks = 0; ks < 2; ++ks)
        bfr[nt][ks] = *(const short8*)(rg + ((wc * 2 + nt) * 2 + ks) * 1024 + laneterm);
  };

  const int NT = K >> 6;   // K-tiles of 64
  const int NI = NT >> 1;  // iterations (2 K-tiles each)

  // Prologue: tile0 fully + tile1 {A0,B0}; wait so tile0 landed.
  stageA(0, 0, 0); stageA(0, 1, 0); stageB(0, 0, 0); stageB(0, 1, 0);
  stageA(1, 0, 1); stageB(1, 0, 1);
  VMW4(); BAR();

  for (int i = 0; i < NI - 1; ++i) {
    const int t1 = 2 * i + 1;
    loadA(0, 0); loadB(0, 0); stageA(1, 1, t1);              BAR(); MMA_QUAD(0, 0); BAR();
    loadB(0, 1);              stageB(1, 1, t1);              BAR(); MMA_QUAD(0, 1); BAR();
    loadA(0, 1); loadB(0, 0); stageA(0, 0, t1 + 1);          BAR(); MMA_QUAD(1, 0); BAR();
    loadB(0, 1);              stageB(0, 0, t1 + 1); VMW4();  BAR(); MMA_QUAD(1, 1); BAR();
    loadA(1, 0); loadB(1, 0); stageA(0, 1, t1 + 1);          BAR(); MMA_QUAD(0, 0); BAR();
    loadB(1, 1);              stageB(0, 1, t1 + 1);          BAR(); MMA_QUAD(0, 1); BAR();
    loadA(1, 1); loadB(1, 0); stageA(1, 0, t1 + 2);          BAR(); MMA_QUAD(1, 0); BAR();
    loadB(1, 1);              stageB(1, 0, t1 + 2); VMW4();  BAR(); MMA_QUAD(1, 1); BAR();
  }
  {  // tail iteration: tiles NT-2, NT-1; no out-of-range prefetch
    const int t1 = NT - 1;
    loadA(0, 0); loadB(0, 0); stageA(1, 1, t1);              BAR(); MMA_QUAD(0, 0); BAR();
    loadB(0, 1);              stageB(1, 1, t1);              BAR(); MMA_QUAD(0, 1); BAR();
    loadA(0, 1); loadB(0, 0);                                BAR(); MMA_QUAD(1, 0); BAR();
    loadB(0, 1);                                    VMW0();  BAR(); MMA_QUAD(1, 1); BAR();
    loadA(1, 0); loadB(1, 0);                                BAR(); MMA_QUAD(0, 0); BAR();
    loadB(1, 1);                                             BAR(); MMA_QUAD(0, 1); BAR();
    loadA(1, 1); loadB(1, 0);                                BAR(); MMA_QUAD(1, 0); BAR();
    loadB(1, 1);                                             BAR(); MMA_QUAD(1, 1);
  }

  // C/D layout (16x16x32): col = lane&15, row = quad*4 + reg.
  const int r0 = bm + wr * 64 + quad * 4;
  const int c0 = bn + wc * 32 + l15;
  if constexpr (EPI == EPI_SCORE) {
    unsigned short* Cz = (unsigned short*)Cv + (long long)z * cBatch;
#pragma unroll
    for (int mh = 0; mh < 2; ++mh)
#pragma unroll
      for (int mt = 0; mt < 4; ++mt)
#pragma unroll
        for (int r = 0; r < 4; ++r) {
          const int row = r0 + mh * 128 + mt * 16 + r;
#pragma unroll
          for (int nh = 0; nh < 2; ++nh)
#pragma unroll
            for (int nt = 0; nt < 2; ++nt)
              Cz[(size_t)row * ldc + c0 + nh * 128 + nt * 16] =
                  f2b(acc[mh][nh][mt][nt][r] * scale);
        }
  } else if constexpr (EPI == EPI_OUT) {
    float* Cz = (float*)Cv + (long long)z * cBatch;
#pragma unroll
    for (int mh = 0; mh < 2; ++mh)
#pragma unroll
      for (int mt = 0; mt < 4; ++mt)
#pragma unroll
        for (int r = 0; r < 4; ++r) {
          const int row = r0 + mh * 128 + mt * 16 + r;
#pragma unroll
          for (int nh = 0; nh < 2; ++nh)
#pragma unroll
            for (int nt = 0; nt < 2; ++nt)
              Cz[(size_t)row * ldc + c0 + nh * 128 + nt * 16] = acc[mh][nh][mt][nt][r];
        }
  } else {
    const float* bp = (z == 0) ? bias : bias2;
    unsigned short* Cz = (unsigned short*)Cv + (long long)z * cBatch;
#pragma unroll
    for (int mh = 0; mh < 2; ++mh)
#pragma unroll
      for (int mt = 0; mt < 4; ++mt)
#pragma unroll
        for (int r = 0; r < 4; ++r) {
          const int row = r0 + mh * 128 + mt * 16 + r;
#pragma unroll
          for (int nh = 0; nh < 2; ++nh)
#pragma unroll
            for (int nt = 0; nt < 2; ++nt) {
              const int col = c0 + nh * 128 + nt * 16;
              float v = acc[mh][nh][mt][nt][r] +
                        (EPI == EPI_BIAS_COL ? bp[col] : bp[row]);
              Cz[(size_t)row * ldc + col] = f2b(v);
            }
        }
  }
}

// ------- row softmax: bf16 scores + raw mask (dtype self-probed) -> bf16 P --
__global__ __launch_bounds__(256) void softmax_rows(const unsigned short* __restrict__ Sc,
                                                    const void* __restrict__ mask,
                                                    unsigned short* __restrict__ P) {
  const size_t r = blockIdx.x;
  const unsigned short* src = Sc + r * SS;
  unsigned short* dst = P + r * SS;
  const int tid = threadIdx.x;
  const int wave = tid >> 6, lane = tid & 63;
  __shared__ int anyv[4];
  __shared__ float red[8];

  // dtype probe: first 256 words are inside row 0 for both layouts.
  unsigned pw = ((const unsigned*)mask)[tid];
  unsigned long long bal = __ballot(pw > 1u);
  if (lane == 0) anyv[wave] = (bal != 0ULL) ? 1 : 0;
  __syncthreads();
  const bool isU8 = (anyv[0] | anyv[1] | anyv[2] | anyv[3]) != 0;

  unsigned mbits = 0;
  if (isU8) {
    uint2 v = *(const uint2*)((const unsigned char*)mask + r * SS + tid * 8);
#pragma unroll
    for (int j = 0; j < 4; ++j) {
      mbits |= (((v.x >> (8 * j)) & 0xffu) ? 1u : 0u) << j;
      mbits |= (((v.y >> (8 * j)) & 0xffu) ? 1u : 0u) << (j + 4);
    }
  } else {
    const uint4* p = (const uint4*)((const int*)mask + r * SS + tid * 8);
    uint4 a = p[0], b = p[1];
    mbits = (a.x ? 1u : 0u) | ((a.y ? 1u : 0u) << 1) | ((a.z ? 1u : 0u) << 2) |
            ((a.w ? 1u : 0u) << 3) | ((b.x ? 1u : 0u) << 4) | ((b.y ? 1u : 0u) << 5) |
            ((b.z ? 1u : 0u) << 6) | ((b.w ? 1u : 0u) << 7);
  }

  union { unsigned short us[8]; uint4 v; } in;
  in.v = *(const uint4*)(src + tid * 8);
  float xs[8];
#pragma unroll
  for (int k = 0; k < 8; ++k)
    xs[k] = ((mbits >> k) & 1u) ? -1.0e9f : b2f(in.us[k]);
  float mx = xs[0];
#pragma unroll
  for (int k = 1; k < 8; ++k) mx = fmaxf(mx, xs[k]);
#pragma unroll
  for (int o = 32; o; o >>= 1) mx = fmaxf(mx, __shfl_xor(mx, o));
  if (lane == 0) red[wave] = mx;
  __syncthreads();
  mx = fmaxf(fmaxf(red[0], red[1]), fmaxf(red[2], red[3]));
  float e[8], s = 0.f;
#pragma unroll
  for (int k = 0; k < 8; ++k) { e[k] = __expf(xs[k] - mx); s += e[k]; }
#pragma unroll
  for (int o = 32; o; o >>= 1) s += __shfl_xor(s, o);
  if (lane == 0) red[4 + wave] = s;
  __syncthreads();
  s = (red[4] + red[5]) + (red[6] + red[7]);
  float inv = 1.0f / s;
  union { unsigned short us[8]; uint4 v; } o;
#pragma unroll
  for (int k = 0; k < 8; ++k) o.us[k] = f2b(e[k] * inv);
  *(uint4*)(dst + tid * 8) = o.v;
}

extern "C" void kernel_launch(void* const* d_in, const int* in_sizes, int n_in,
                              void* d_out, int out_size, void* d_ws, size_t ws_size,
                              hipStream_t stream) {
  const float* query = (const float*)d_in[0];
  const float* key   = (const float*)d_in[1];
  const float* value = (const float*)d_in[2];
  const void*  mask  = d_in[3];                 // bool: u8 or i32, self-probed
  const float* Wq = (const float*)d_in[4];
  const float* bq = (const float*)d_in[5];
  const float* Wk = (const float*)d_in[6];
  const float* bk = (const float*)d_in[7];
  const float* Wv = (const float*)d_in[8];
  const float* bv = (const float*)d_in[9];
  float* out = (float*)d_out;

  char* ws = (char*)d_ws;
  const size_t MB = 1024 * 1024;
  unsigned short* qin = (unsigned short*)(ws + 0 * MB);    // 8192x1024 bf16, 16MB
  unsigned short* kin = (unsigned short*)(ws + 16 * MB);
  unsigned short* vin = (unsigned short*)(ws + 32 * MB);
  unsigned short* Wqb = (unsigned short*)(ws + 48 * MB);   // 1024x1024 bf16, 2MB
  unsigned short* Wkb = (unsigned short*)(ws + 50 * MB);
  unsigned short* Wvb = (unsigned short*)(ws + 52 * MB);
  unsigned short* qb  = (unsigned short*)(ws + 54 * MB);   // q proj bf16, 16MB
  unsigned short* kb  = (unsigned short*)(ws + 70 * MB);
  unsigned short* vT  = (unsigned short*)(ws + 86 * MB);   // v^T [1024][8192] bf16
  unsigned short* Sc  = (unsigned short*)(ws + 102 * MB);  // scores bf16, 32MB
  unsigned short* P   = (unsigned short*)(ws + 134 * MB);  // softmax bf16, 32MB

  dim3 blk(256), blk512(512);

  // fp32 -> bf16 for all six tensors (one dispatch)
  cvt_all<<<dim3(4608, 1, 3), blk, 0, stream>>>(
      query, key, value, Wq, Wk, Wv, qin, kin, vin, Wqb, Wkb, Wvb);

  // q = query @ Wq^T + bq ; k = key @ Wk^T + bk   (batched z=2, bf16 out)
  gemm256<EPI_BIAS_COL><<<dim3(32, 4, 2), blk512, 0, stream>>>(
      qin, 1024, 8388608LL, Wqb, 1024, 1048576LL, qb, 1024, 8388608LL,
      1024, bq, bk, 0.f);

  // v^T[n][m] = sum_d Wv[n,d] * value[m,d] + bv[n]  -> [1024][8192] bf16
  gemm256<EPI_BIAS_ROW><<<dim3(4, 32, 1), blk512, 0, stream>>>(
      Wvb, 1024, 0, vin, 1024, 0, vT, 8192, 0, 1024, bv, bv, 0.f);

  // scores[b][m][n] = (q_m . k_n) / 32   (bf16, unmasked)
  gemm256<EPI_SCORE><<<dim3(8, 8, BB), blk512, 0, stream>>>(
      qb, 1024, (long long)SS * 1024, kb, 1024, (long long)SS * 1024,
      Sc, SS, (long long)SS * SS, 1024, nullptr, nullptr, 0.03125f);

  // P = softmax(mask ? -1e9 : scores) rows, bf16
  softmax_rows<<<dim3(BB * SS), blk, 0, stream>>>(Sc, mask, P);

  // out[b][m][n] = sum_k P[m][k] * vT[n][k]   (fp32 out)
  gemm256<EPI_OUT><<<dim3(8, 4, BB), blk512, 0, stream>>>(
      P, SS, (long long)SS * SS, vT, 8192, (long long)SS,
      out, 1024, (long long)SS * 1024, SS, nullptr, nullptr, 1.f);
}